// Round 1
// baseline (982.000 us; speedup 1.0000x reference)
//
#include <hip/hip_runtime.h>

#define B 128
#define N 1024
#define L 512
#define D 64

// ws layout: float sims[3*B] | int cnts[2*B]  (cnts[0..B)=ntok, cnts[B..2B)=nreg)

__global__ void init_kernel(const float* __restrict__ tmask,
                            const float* __restrict__ imask,
                            float* __restrict__ sims,
                            int* __restrict__ cnts) {
    int blk = blockIdx.x;   // 0..2B-1
    int tid = threadIdx.x;  // 256
    __shared__ float red[256];
    float s = 0.f;
    if (blk < B) {
        for (int i = tid; i < N; i += 256) s += tmask[blk * N + i];
    } else {
        int r = blk - B;
        for (int i = tid; i < L; i += 256) s += imask[r * L + i];
    }
    red[tid] = s;
    __syncthreads();
    for (int off = 128; off > 0; off >>= 1) {
        if (tid < off) red[tid] += red[tid + off];
        __syncthreads();
    }
    if (tid == 0) cnts[blk] = (int)(red[0] + 0.5f);
    // zero the sim accumulators (ws is poisoned 0xAA before every launch)
    if (blk < B && tid < 3) sims[tid * B + blk] = 0.f;
}

// One thread per token; T row (64 floats) in VGPRs; I rows are wave-uniform
// addresses -> scalar loads. grid = 3*B*(N/256) blocks of 256.
__global__ __launch_bounds__(256, 2) void sim_kernel(
        const float* __restrict__ T, const float* __restrict__ I,
        const int* __restrict__ Iimp, const int* __restrict__ Simp,
        const int* __restrict__ cnts, float* __restrict__ sims) {
    int blk = blockIdx.x;
    int chunk = blk & 3;        // token chunk of 256 (N/256 = 4)
    int bs = blk >> 2;          // 0..3B-1
    int b = bs & (B - 1);
    int s = bs >> 7;            // bs / B
    int Tb = b, Ib = b;
    if (s == 1) Tb = Simp[b];       // impostor sentence: T,tmask from S_imp[b]
    else if (s == 2) Ib = Iimp[b];  // impostor image: I,imask from I_imp[b]
    int ntok = cnts[Tb];
    int nreg = cnts[B + Ib];
    int n0 = chunk * 256;
    if (n0 >= ntok) return;     // whole chunk masked out (uniform exit)

    int tid = threadIdx.x;
    int n = n0 + tid;           // token index, always < N
    float4 tr[16];
    const float4* Tr4 = (const float4*)(T + ((size_t)Tb * N + n) * D);
#pragma unroll
    for (int i = 0; i < 16; ++i) tr[i] = Tr4[i];

    const float* Ibase = I + (size_t)Ib * L * D;
    float mx = -3.4e38f;
    for (int l = 0; l < nreg; ++l) {
        const float4* Ir = (const float4*)(Ibase + (size_t)l * D);
        float a0 = 0.f, a1 = 0.f, a2 = 0.f, a3 = 0.f;
#pragma unroll
        for (int i = 0; i < 16; ++i) {
            float4 iv = Ir[i];   // uniform address -> s_load, broadcast to lanes
            a0 = fmaf(tr[i].x, iv.x, a0);
            a1 = fmaf(tr[i].y, iv.y, a1);
            a2 = fmaf(tr[i].z, iv.z, a2);
            a3 = fmaf(tr[i].w, iv.w, a3);
        }
        mx = fmaxf(mx, (a0 + a1) + (a2 + a3));
    }
    float contrib = (n < ntok) ? mx : 0.f;
    // wave reduce (64 lanes), lane 0 of each wave holds the wave sum
    for (int off = 32; off > 0; off >>= 1) contrib += __shfl_down(contrib, off);
    __shared__ float wsum[4];
    if ((tid & 63) == 0) wsum[tid >> 6] = contrib;
    __syncthreads();
    if (tid == 0) {
        float tot = wsum[0] + wsum[1] + wsum[2] + wsum[3];
        atomicAdd(&sims[s * B + b], tot / (float)ntok);
    }
}

__global__ void loss_kernel(const float* __restrict__ sims,
                            float* __restrict__ out) {
    int tid = threadIdx.x;  // 128 threads
    float anc = sims[tid];
    float simp = sims[B + tid];
    float iimp = sims[2 * B + tid];
    float per = fmaxf(1.f + iimp - anc, 0.f) + fmaxf(1.f + simp - anc, 0.f);
    for (int off = 32; off > 0; off >>= 1) per += __shfl_down(per, off);
    __shared__ float w2[2];
    if ((tid & 63) == 0) w2[tid >> 6] = per;
    __syncthreads();
    if (tid == 0) out[0] = (w2[0] + w2[1]) / (float)B;
}

extern "C" void kernel_launch(void* const* d_in, const int* in_sizes, int n_in,
                              void* d_out, int out_size, void* d_ws, size_t ws_size,
                              hipStream_t stream) {
    const float* T     = (const float*)d_in[0];  // (B,N,D)
    const float* I     = (const float*)d_in[1];  // (B,L,D)
    const float* tmask = (const float*)d_in[2];  // (B,N)
    const float* imask = (const float*)d_in[3];  // (B,L)
    const int*   Iimp  = (const int*)d_in[4];    // (B,)
    const int*   Simp  = (const int*)d_in[5];    // (B,)
    float* sims = (float*)d_ws;
    int*   cnts = (int*)((char*)d_ws + 3 * B * sizeof(float));

    init_kernel<<<2 * B, 256, 0, stream>>>(tmask, imask, sims, cnts);
    sim_kernel<<<3 * B * (N / 256), 256, 0, stream>>>(T, I, Iimp, Simp, cnts, sims);
    loss_kernel<<<1, 128, 0, stream>>>(sims, (float*)d_out);
}

// Round 2
// 132.534 us; speedup vs baseline: 7.4094x; 7.4094x over previous
//
#include <hip/hip_runtime.h>

#define B 128
#define N 1024
#define L 512
#define D 64

typedef float f32x4 __attribute__((ext_vector_type(4)));
typedef short bf16x8 __attribute__((ext_vector_type(8)));

// ws layout: float sims[3*B] | int cnts[2*B]

__global__ void init_kernel(const float* __restrict__ tmask,
                            const float* __restrict__ imask,
                            float* __restrict__ sims,
                            int* __restrict__ cnts) {
    int blk = blockIdx.x;   // 0..2B-1
    int tid = threadIdx.x;  // 256
    __shared__ float red[256];
    float s = 0.f;
    if (blk < B) {
        for (int i = tid; i < N; i += 256) s += tmask[blk * N + i];
    } else {
        int r = blk - B;
        for (int i = tid; i < L; i += 256) s += imask[r * L + i];
    }
    red[tid] = s;
    __syncthreads();
    for (int off = 128; off > 0; off >>= 1) {
        if (tid < off) red[tid] += red[tid + off];
        __syncthreads();
    }
    if (tid == 0) cnts[blk] = (int)(red[0] + 0.5f);
    if (blk < B && tid < 3) sims[tid * B + blk] = 0.f;
}

// RNE fp32 -> bf16, packed pair into one uint
__device__ inline unsigned int pack_bf16(float lo, float hi) {
    unsigned int a = __float_as_uint(lo), b = __float_as_uint(hi);
    a = (a + 0x7fffu + ((a >> 16) & 1u)) >> 16;
    b = (b + 0x7fffu + ((b >> 16) & 1u)) & 0xffff0000u;
    return a | b;
}

#define RSTRIDE 72  // bf16 elems per staged region row (72*2=144B, 16B aligned, 2-way banks = free)

// grid = 3*B*(N/256) blocks of 256 threads (4 waves).
// Block: one (s,b) problem, 256-token range. Wave: 64 tokens (4 MFMA token tiles).
__global__ __launch_bounds__(256) void sim_kernel(
        const float* __restrict__ T, const float* __restrict__ I,
        const int* __restrict__ Iimp, const int* __restrict__ Simp,
        const int* __restrict__ cnts, float* __restrict__ sims) {
    int blk = blockIdx.x;
    int chunk = blk & 3;        // token chunk of 256 (N/256 = 4)
    int bs = blk >> 2;          // 0..3B-1
    int b = bs & (B - 1);
    int s = bs >> 7;
    int Tb = b, Ib = b;
    if (s == 1) Tb = Simp[b];
    else if (s == 2) Ib = Iimp[b];
    int ntok = cnts[Tb];
    int nreg = cnts[B + Ib];
    int tok0 = chunk * 256;
    if (tok0 >= ntok) return;   // uniform block exit, before any barrier

    int tid = threadIdx.x;
    int w = tid >> 6;           // wave 0..3
    int lane = tid & 63;
    int q = lane >> 4;          // 0..3
    int c = lane & 15;          // 0..15

    __shared__ unsigned short ldsI[64 * RSTRIDE];  // 9.2 KB staged bf16 I chunk
    __shared__ float wsum[4];

    // ---- A fragments: 4 token tiles x 2 K-halves, converted fp32->bf16 ----
    int wt0 = tok0 + w * 64;    // wave token base
    bf16x8 afrag[4][2];
#pragma unroll
    for (int tt = 0; tt < 4; ++tt) {
        const float* trow = T + ((size_t)Tb * N + wt0 + tt * 16 + c) * D;
#pragma unroll
        for (int h = 0; h < 2; ++h) {
            const float4* p = (const float4*)(trow + h * 32 + q * 8);
            float4 f0 = p[0], f1 = p[1];
            unsigned int u[4];
            u[0] = pack_bf16(f0.x, f0.y);
            u[1] = pack_bf16(f0.z, f0.w);
            u[2] = pack_bf16(f1.x, f1.y);
            u[3] = pack_bf16(f1.z, f1.w);
            afrag[tt][h] = *(bf16x8*)u;
        }
    }

    float mx[4][4];
#pragma unroll
    for (int tt = 0; tt < 4; ++tt)
#pragma unroll
        for (int i = 0; i < 4; ++i) mx[tt][i] = -3.4e38f;

    const float* Ibase = I + (size_t)Ib * L * D;

    // ---- loop over 64-region chunks ----
    for (int r0 = 0; r0 < nreg; r0 += 64) {
        // stage chunk into LDS as bf16: thread -> (region r, 16-float segment)
        {
            int r = tid >> 2;
            int dseg = (tid & 3) * 16;
            int gr = r0 + r;
            float4 f[4];
            if (gr < nreg) {
                const float4* p = (const float4*)(Ibase + (size_t)gr * D + dseg);
#pragma unroll
                for (int i = 0; i < 4; ++i) f[i] = p[i];
            } else {
#pragma unroll
                for (int i = 0; i < 4; ++i) f[i] = make_float4(0.f, 0.f, 0.f, 0.f);
            }
            unsigned int u[8];
#pragma unroll
            for (int i = 0; i < 4; ++i) {
                u[2 * i]     = pack_bf16(f[i].x, f[i].y);
                u[2 * i + 1] = pack_bf16(f[i].z, f[i].w);
            }
            uint4* dst = (uint4*)&ldsI[r * RSTRIDE + dseg];
            dst[0] = *(uint4*)&u[0];
            dst[1] = *(uint4*)&u[4];
        }
        __syncthreads();

        int nrt = nreg - r0;
        nrt = nrt > 64 ? 4 : ((nrt + 15) >> 4);
#pragma unroll 1
        for (int rt = 0; rt < nrt; ++rt) {
            int rr = rt * 16 + c;                       // region within chunk
            bf16x8 bf0 = *(bf16x8*)&ldsI[rr * RSTRIDE + q * 8];
            bf16x8 bf1 = *(bf16x8*)&ldsI[rr * RSTRIDE + 32 + q * 8];
            bool valid = (r0 + rt * 16 + c) < nreg;
#pragma unroll
            for (int tt = 0; tt < 4; ++tt) {
                f32x4 acc = {0.f, 0.f, 0.f, 0.f};
                acc = __builtin_amdgcn_mfma_f32_16x16x32_bf16(afrag[tt][0], bf0, acc, 0, 0, 0);
                acc = __builtin_amdgcn_mfma_f32_16x16x32_bf16(afrag[tt][1], bf1, acc, 0, 0, 0);
                if (valid) {
#pragma unroll
                    for (int i = 0; i < 4; ++i) mx[tt][i] = fmaxf(mx[tt][i], acc[i]);
                }
            }
        }
        __syncthreads();
    }

    // ---- cross-lane max over the 16 cols in each row group ----
#pragma unroll
    for (int m = 1; m < 16; m <<= 1) {
#pragma unroll
        for (int tt = 0; tt < 4; ++tt)
#pragma unroll
            for (int i = 0; i < 4; ++i)
                mx[tt][i] = fmaxf(mx[tt][i], __shfl_xor(mx[tt][i], m));
    }

    // ---- masked token sum ----
    float lsum = 0.f;
    if (c == 0) {
#pragma unroll
        for (int tt = 0; tt < 4; ++tt)
#pragma unroll
            for (int i = 0; i < 4; ++i) {
                int row = wt0 + tt * 16 + q * 4 + i;
                if (row < ntok) lsum += mx[tt][i];
            }
    }
    for (int off = 32; off > 0; off >>= 1) lsum += __shfl_down(lsum, off);
    if (lane == 0) wsum[w] = lsum;
    __syncthreads();
    if (tid == 0) {
        float tot = wsum[0] + wsum[1] + wsum[2] + wsum[3];
        atomicAdd(&sims[s * B + b], tot / (float)ntok);
    }
}

__global__ void loss_kernel(const float* __restrict__ sims,
                            float* __restrict__ out) {
    int tid = threadIdx.x;  // 128 threads
    float anc = sims[tid];
    float simp = sims[B + tid];
    float iimp = sims[2 * B + tid];
    float per = fmaxf(1.f + iimp - anc, 0.f) + fmaxf(1.f + simp - anc, 0.f);
    for (int off = 32; off > 0; off >>= 1) per += __shfl_down(per, off);
    __shared__ float w2[2];
    if ((tid & 63) == 0) w2[tid >> 6] = per;
    __syncthreads();
    if (tid == 0) out[0] = (w2[0] + w2[1]) / (float)B;
}

extern "C" void kernel_launch(void* const* d_in, const int* in_sizes, int n_in,
                              void* d_out, int out_size, void* d_ws, size_t ws_size,
                              hipStream_t stream) {
    const float* T     = (const float*)d_in[0];
    const float* I     = (const float*)d_in[1];
    const float* tmask = (const float*)d_in[2];
    const float* imask = (const float*)d_in[3];
    const int*   Iimp  = (const int*)d_in[4];
    const int*   Simp  = (const int*)d_in[5];
    float* sims = (float*)d_ws;
    int*   cnts = (int*)((char*)d_ws + 3 * B * sizeof(float));

    init_kernel<<<2 * B, 256, 0, stream>>>(tmask, imask, sims, cnts);
    sim_kernel<<<3 * B * (N / 256), 256, 0, stream>>>(T, I, Iimp, Simp, cnts, sims);
    loss_kernel<<<1, 128, 0, stream>>>(sims, (float*)d_out);
}